// Round 1
// baseline (3658.398 us; speedup 1.0000x reference)
//
#include <hip/hip_runtime.h>
#include <hip/hip_bf16.h>
#include <math.h>

#define TSTEPS 100
#define BDIM   16
#define HDIM   512
#define NLAYER 3
#define VDIM   32000
#define NREC   128      // recurrence WGs (4 hidden units each)
#define NGEMM  125      // logits-GEMM WGs (256 vocab cols each)
#define NCOLS  256
#define CHUNK  8
#define NCHUNK 13       // ceil(100/8)

#define WROW   1032     // padded LDS row stride (bf16 elems) for weights: 2-way bank alias only
#define AROW   520      // padded LDS row stride for gemm A tile

// recurrence LDS map (bytes): Wlds[3][16][1032] bf16 = 99072 | bias[48] f32 @99072 |
//   pC[4][16][17] f32 @99264 | cst[3][16][4] f32 @103616  -> 104384 total
// gemm LDS map: At[8][16][520] bf16 = 133120
#define SMEM_BYTES 133120

typedef __bf16 bf16x8 __attribute__((ext_vector_type(8)));
typedef float  f32x4  __attribute__((ext_vector_type(4)));

__device__ __forceinline__ float sigm_f(float x) { return 1.0f / (1.0f + __expf(-x)); }

// Wait until all 128 recurrence flags >= tgt (i.e. every WG finished hop tgt-1).
// Poison 0xAAAAAAAA is negative -> "not ready", so no flag init is needed.
__device__ __forceinline__ void waitFlags(int* flags, int tgt, int lane) {
  int guard = 0;
  while (true) {
    int a0 = __hip_atomic_load(flags + 2 * lane,     __ATOMIC_RELAXED, __HIP_MEMORY_SCOPE_AGENT);
    int a1 = __hip_atomic_load(flags + 2 * lane + 1, __ATOMIC_RELAXED, __HIP_MEMORY_SCOPE_AGENT);
    if (__ballot((a0 >= tgt) && (a1 >= tgt)) == ~0ull) break;
    __builtin_amdgcn_s_sleep(1);
    if (++guard > (1 << 22)) break;   // failsafe: turn a residency bug into a wrong answer, not a hang
  }
  __threadfence();                    // acquire: invalidate L1 so subsequent h/x loads are fresh
}

__global__ __launch_bounds__(256) void rgn_kernel(
    const float* __restrict__ ctx,  const int* __restrict__ sid,
    const float* __restrict__ stab,
    const float* __restrict__ wih,  const float* __restrict__ whh,
    const float* __restrict__ bih,  const float* __restrict__ bhh,
    const float* __restrict__ wout, const float* __restrict__ boutg,
    float* __restrict__ out,
    int* flags, __bf16* h2, __bf16* hbuf)
{
  extern __shared__ char smem[];
  const int tid  = threadIdx.x;
  const int lane = tid & 63;
  const int wid  = tid >> 6;
  const int blk  = blockIdx.x;

  if (blk < NREC) {
    // ================= recurrence WG: owns hidden units [4r, 4r+4) of every layer =================
    __bf16* Wlds = (__bf16*)smem;                 // [3][16][WROW], row rr = q*4+u (q=i,f,g,o)
    float*  biasL = (float*)(smem + 99072);       // [3][16]  b_ih+b_hh
    float*  pC    = (float*)(smem + 99264);       // [4][16][17] partial C per wave
    float*  cst   = (float*)(smem + 103616);      // [3][16][4] fp32 cell state
    const int r = blk;

    // ---- one-time: stage this WG's gate-row weights (x|h concat, K=1024) into LDS as bf16 ----
    for (int idx = tid; idx < NLAYER * 16 * 256; idx += 256) {
      int k4 = idx & 255;                 // 4-float group within K=1024
      int rr = (idx >> 8) & 15;
      int l  = idx >> 12;
      int q = rr >> 2, u = rr & 3;
      int grow = q * 512 + 4 * r + u;     // gate row in W_ih / W_hh
      int k = k4 * 4;
      const float* src = (k < 512) ? &wih[((size_t)l * 2048 + grow) * 512 + k]
                                   : &whh[((size_t)l * 2048 + grow) * 512 + (k - 512)];
      float4 v = *(const float4*)src;
      __bf16* d = &Wlds[(l * 16 + rr) * WROW + k];
      d[0] = (__bf16)v.x; d[1] = (__bf16)v.y; d[2] = (__bf16)v.z; d[3] = (__bf16)v.w;
    }
    if (tid < NLAYER * 16) {
      int l = tid >> 4, rr = tid & 15;
      int q = rr >> 2, u = rr & 3;
      int grow = q * 512 + 4 * r + u;
      biasL[tid] = bih[l * 2048 + grow] + bhh[l * 2048 + grow];
    }
    if (tid < NLAYER * 16 * 4) cst[tid] = 0.0f;
    __syncthreads();

    const int m16 = lane & 15;            // MFMA A row (batch) / B row (gate)
    const int ko8 = (lane >> 4) * 8;      // k sub-offset within a K=32 MFMA slice

    int t = 0, l = 0;
    for (int hop = 0; hop < NLAYER * TSTEPS; ++hop) {
      const int cur = t & 1, prev = cur ^ 1;
      bf16x8 afrag[8];

      // waves 2,3: prefetch recurrent-h fragments (producers covered by PREVIOUS hop's acquire)
      if (wid >= 2) {
        const int kp = (wid - 2) * 256 + ko8;           // k' in [0,512)
        if (t == 0) {
          const float* hs = &ctx[m16 * HDIM + kp];
          #pragma unroll
          for (int i = 0; i < 8; ++i) {
            const float* p = hs + 32 * i; bf16x8 a;
            #pragma unroll
            for (int j = 0; j < 8; ++j) a[j] = (__bf16)p[j];
            afrag[i] = a;
          }
        } else {
          const __bf16* hs = (l < 2) ? &hbuf[((prev * 2 + l) * 16 + m16) * HDIM + kp]
                                     : &h2[((size_t)(t - 1) * 16 + m16) * HDIM + kp];
          #pragma unroll
          for (int i = 0; i < 8; ++i) afrag[i] = *(const bf16x8*)(hs + 32 * i);
        }
      }
      if (wid == 0 && hop > 0) waitFlags(flags, hop, lane);  // all WGs finished hop-1
      __syncthreads();
      // waves 0,1: load x fragments (only ready after the flag wait)
      if (wid < 2) {
        const int kp = wid * 256 + ko8;
        if (l == 0) {
          if (t == 0) {
            const int s = sid[m16];
            const float* xs = &stab[s * HDIM + kp];
            #pragma unroll
            for (int i = 0; i < 8; ++i) {
              const float* p = xs + 32 * i; bf16x8 a;
              #pragma unroll
              for (int j = 0; j < 8; ++j) a[j] = (__bf16)p[j];
              afrag[i] = a;
            }
          } else {
            const __bf16* xs = &h2[((size_t)(t - 1) * 16 + m16) * HDIM + kp];
            #pragma unroll
            for (int i = 0; i < 8; ++i) afrag[i] = *(const bf16x8*)(xs + 32 * i);
          }
        } else {
          const __bf16* xs = &hbuf[((cur * 2 + (l - 1)) * 16 + m16) * HDIM + kp];
          #pragma unroll
          for (int i = 0; i < 8; ++i) afrag[i] = *(const bf16x8*)(xs + 32 * i);
        }
      }
      // MFMA over this wave's K-quarter: C[m=batch][n=gate row]
      f32x4 acc = {0.f, 0.f, 0.f, 0.f};
      const __bf16* wrow = &Wlds[(l * 16 + m16) * WROW + wid * 256 + ko8];
      #pragma unroll
      for (int i = 0; i < 8; ++i) {
        bf16x8 b = *(const bf16x8*)(wrow + 32 * i);
        acc = __builtin_amdgcn_mfma_f32_16x16x32_bf16(afrag[i], b, acc, 0, 0, 0);
      }
      #pragma unroll
      for (int rr2 = 0; rr2 < 4; ++rr2)
        pC[(wid * 16 + ((lane >> 4) * 4 + rr2)) * 17 + m16] = acc[rr2];
      __syncthreads();

      // wave 0: cross-wave reduce + LSTM pointwise + publish h slice + release flag
      if (wid == 0) {
        const int m = lane >> 2, u = lane & 3;
        float g[4];
        #pragma unroll
        for (int q = 0; q < 4; ++q) {
          float s = 0.f;
          #pragma unroll
          for (int w = 0; w < 4; ++w) s += pC[(w * 16 + m) * 17 + q * 4 + u];
          g[q] = s + biasL[l * 16 + q * 4 + u];
        }
        const int cidx = (l * 16 + m) * 4 + u;
        float c  = cst[cidx];
        float ig = sigm_f(g[0]), fg = sigm_f(g[1]), gg = tanhf(g[2]), og = sigm_f(g[3]);
        float cn = fg * c + ig * gg;
        float hn = og * tanhf(cn);
        cst[cidx] = cn;
        __bf16 hb = (__bf16)hn;
        if (l < 2) hbuf[((cur * 2 + l) * 16 + m) * HDIM + 4 * r + u] = hb;
        else       h2[((size_t)t * 16 + m) * HDIM + 4 * r + u] = hb;   // persistent top-layer history
        __threadfence();   // release: h visible device-wide before flag
        if (lane == 0)
          __hip_atomic_store(&flags[r], hop + 1, __ATOMIC_RELAXED, __HIP_MEMORY_SCOPE_AGENT);
      }
      if (++l == NLAYER) { l = 0; ++t; }
    }
  } else if (blk < NREC + NGEMM) {
    // ================= logits GEMM WG: fixed 256-col W_out slice, chunked over steps =================
    __bf16* At = (__bf16*)smem;                   // [CHUNK][16][AROW]
    const int g = blk - NREC;
    const int vbase = g * NCOLS;
    const int n16 = lane & 15;
    const int ko8 = (lane >> 4) * 8;

    for (int ci = 0; ci < NCHUNK; ++ci) {
      const int c0 = ci * CHUNK;
      const int ns = (TSTEPS - c0 < CHUNK) ? (TSTEPS - c0) : CHUNK;
      const int tlast = c0 + ns - 1;
      if (wid == 0) waitFlags(flags, 3 * tlast + 3, lane);   // all steps of this chunk done
      __syncthreads();
      // stage h_top for the chunk into LDS (padded rows)
      for (int s = 0; s < ns; ++s) {
        const uint4* src = (const uint4*)&h2[(size_t)(c0 + s) * 16 * HDIM];
        #pragma unroll
        for (int it = 0; it < 4; ++it) {
          int idx = tid + 256 * it;                  // 0..1023 -> (m, k8)
          int m = idx >> 6, k8 = idx & 63;
          uint4 v = src[idx];
          *(uint4*)&At[(s * 16 + m) * AROW + k8 * 8] = v;
        }
      }
      __syncthreads();
      for (int nt = wid; nt < 16; nt += 4) {
        const int vrow = vbase + nt * 16 + n16;      // B row = W_out row (B^T trick)
        bf16x8 bfr[16];
        #pragma unroll
        for (int j = 0; j < 16; ++j) {
          const float* p = &wout[(size_t)vrow * HDIM + j * 32 + ko8];
          bf16x8 b;
          #pragma unroll
          for (int e = 0; e < 8; ++e) b[e] = (__bf16)p[e];
          bfr[j] = b;
        }
        const float bo = boutg[vrow];
        for (int s = 0; s < ns; ++s) {
          f32x4 acc = {0.f, 0.f, 0.f, 0.f};
          const __bf16* arow = &At[(s * 16 + n16) * AROW + ko8];
          #pragma unroll
          for (int j = 0; j < 16; ++j) {
            bf16x8 a = *(const bf16x8*)(arow + 32 * j);
            acc = __builtin_amdgcn_mfma_f32_16x16x32_bf16(a, bfr[j], acc, 0, 0, 0);
          }
          const int tt = c0 + s;
          #pragma unroll
          for (int rr2 = 0; rr2 < 4; ++rr2) {
            const int m = (lane >> 4) * 4 + rr2;     // C row = batch
            out[((size_t)m * TSTEPS + tt) * VDIM + vrow] = acc[rr2] + bo;
          }
        }
      }
    }
  }
}

extern "C" void kernel_launch(void* const* d_in, const int* in_sizes, int n_in,
                              void* d_out, int out_size, void* d_ws, size_t ws_size,
                              hipStream_t stream) {
  const float* ctx  = (const float*)d_in[0];
  const int*   sid  = (const int*)  d_in[1];
  const float* stab = (const float*)d_in[2];
  const float* wih  = (const float*)d_in[3];
  const float* whh  = (const float*)d_in[4];
  const float* bih  = (const float*)d_in[5];
  const float* bhh  = (const float*)d_in[6];
  const float* wout = (const float*)d_in[7];
  const float* bout = (const float*)d_in[8];
  float* out = (float*)d_out;

  char* ws = (char*)d_ws;
  int*    flags = (int*)ws;                                          // 128 ints (poison = not ready)
  __bf16* h2    = (__bf16*)(ws + 1024);                              // [100][16][512] top-layer history
  __bf16* hbuf  = (__bf16*)(ws + 1024 + (size_t)TSTEPS * 16 * HDIM * 2);  // [2][2][16][512] parity h

  (void)in_sizes; (void)n_in; (void)out_size; (void)ws_size;
  hipFuncSetAttribute((const void*)rgn_kernel, hipFuncAttributeMaxDynamicSharedMemorySize, SMEM_BYTES);
  rgn_kernel<<<dim3(NREC + NGEMM), dim3(256), SMEM_BYTES, stream>>>(
      ctx, sid, stab, wih, whh, bih, bhh, wout, bout, out, flags, h2, hbuf);
}

// Round 2
// 2012.886 us; speedup vs baseline: 1.8175x; 1.8175x over previous
//
#include <hip/hip_runtime.h>
#include <hip/hip_bf16.h>
#include <math.h>

#define TSTEPS 100
#define BDIM   16
#define HDIM   512
#define NLAYER 3
#define VDIM   32000
#define NREC   128      // recurrence WGs (4 hidden units each)
#define NGEMM  125      // logits-GEMM WGs (256 vocab cols each)
#define NCOLS  256
#define CHUNK  8
#define NCHUNK 13       // ceil(100/8)

#define WROW   1032     // padded LDS row stride (bf16 elems) for weights
#define AROW   520      // padded LDS row stride for gemm A tile

// recurrence LDS map (bytes): Wlds[3][16][1032] bf16 = 99072 | bias[48] f32 @99072 |
//   pC[4][16][17] f32 @99264 | cst[3][16][4] f32 @103616  -> 104384 total
// gemm LDS map: At[8][16][520] bf16 = 133120
#define SMEM_BYTES 133120

typedef __bf16 bf16x8 __attribute__((ext_vector_type(8)));
typedef float  f32x4  __attribute__((ext_vector_type(4)));

__device__ __forceinline__ float sigm_f(float x) { return 1.0f / (1.0f + __expf(-x)); }
__device__ __forceinline__ float tanh_f(float x) { float e = __expf(2.0f * x); return 1.0f - 2.0f / (e + 1.0f); }

// 16B fragment load that bypasses L1/L2 (reads the coherence point / L3).
__device__ __forceinline__ bf16x8 frag_ld(const __bf16* p) {
  const unsigned long long* q = (const unsigned long long*)p;
  union { unsigned long long u[2]; bf16x8 v; } r;
  r.u[0] = __hip_atomic_load(q,     __ATOMIC_RELAXED, __HIP_MEMORY_SCOPE_AGENT);
  r.u[1] = __hip_atomic_load(q + 1, __ATOMIC_RELAXED, __HIP_MEMORY_SCOPE_AGENT);
  return r.v;
}

// Wait until all 128 recurrence flags >= tgt. NO cache-wide fences: flags are
// relaxed agent-scope loads (L2-bypass); data loads afterwards are also
// L2-bypass, and in-order wave issue gives us acquire ordering for free.
// Poison 0xAAAAAAAA is negative -> "not ready", so no flag init is needed.
template <int SLP>
__device__ __forceinline__ void waitFlags(int* flags, int tgt, int lane) {
  int guard = 0;
  while (true) {
    int a0 = __hip_atomic_load(flags + 2 * lane,     __ATOMIC_RELAXED, __HIP_MEMORY_SCOPE_AGENT);
    int a1 = __hip_atomic_load(flags + 2 * lane + 1, __ATOMIC_RELAXED, __HIP_MEMORY_SCOPE_AGENT);
    if (__ballot((a0 >= tgt) && (a1 >= tgt)) == ~0ull) break;
    __builtin_amdgcn_s_sleep(SLP);
    if (++guard > (1 << 22)) break;   // failsafe: wrong answer, not a hang
  }
  asm volatile("" ::: "memory");      // compiler barrier only
}

__global__ __launch_bounds__(256) void rgn_kernel(
    const float* __restrict__ ctx,  const int* __restrict__ sid,
    const float* __restrict__ stab,
    const float* __restrict__ wih,  const float* __restrict__ whh,
    const float* __restrict__ bih,  const float* __restrict__ bhh,
    const float* __restrict__ wout, const float* __restrict__ boutg,
    float* __restrict__ out,
    int* flags, __bf16* h2, __bf16* hbuf, __bf16* wbf)
{
  extern __shared__ char smem[];
  const int tid  = threadIdx.x;
  const int lane = tid & 63;
  const int wid  = tid >> 6;
  const int blk  = blockIdx.x;

  if (blk < NREC) {
    // ================= recurrence WG: owns hidden units [4r, 4r+4) of every layer =================
    __bf16* Wlds = (__bf16*)smem;                 // [3][16][WROW], row rr = q*4+u (q=i,f,g,o)
    float*  biasL = (float*)(smem + 99072);       // [3][16]  b_ih+b_hh
    float*  pC    = (float*)(smem + 99264);       // [4][16][17] partial C per wave
    float*  cst   = (float*)(smem + 103616);      // [3][16][4] fp32 cell state
    const int r = blk;

    // ---- one-time: stage this WG's gate-row weights (x|h concat, K=1024) into LDS as bf16 ----
    for (int idx = tid; idx < NLAYER * 16 * 256; idx += 256) {
      int k4 = idx & 255;
      int rr = (idx >> 8) & 15;
      int l  = idx >> 12;
      int q = rr >> 2, u = rr & 3;
      int grow = q * 512 + 4 * r + u;
      int k = k4 * 4;
      const float* src = (k < 512) ? &wih[((size_t)l * 2048 + grow) * 512 + k]
                                   : &whh[((size_t)l * 2048 + grow) * 512 + (k - 512)];
      float4 v = *(const float4*)src;
      __bf16* d = &Wlds[(l * 16 + rr) * WROW + k];
      d[0] = (__bf16)v.x; d[1] = (__bf16)v.y; d[2] = (__bf16)v.z; d[3] = (__bf16)v.w;
    }
    if (tid < NLAYER * 16) {
      int l = tid >> 4, rr = tid & 15;
      int q = rr >> 2, u = rr & 3;
      int grow = q * 512 + 4 * r + u;
      biasL[tid] = bih[l * 2048 + grow] + bhh[l * 2048 + grow];
    }
    if (tid < NLAYER * 16 * 4) cst[tid] = 0.0f;
    __syncthreads();

    const int m16 = lane & 15;            // MFMA A row (batch) / B row (gate)
    const int ko8 = (lane >> 4) * 8;      // k sub-offset within a K=32 MFMA slice

    int t = 0, l = 0;
    for (int hop = 0; hop < NLAYER * TSTEPS; ++hop) {
      const int cur = t & 1, prev = cur ^ 1;
      bf16x8 afrag[8];

      // waves 2,3: prefetch recurrent-h fragments (3 hops old -> covered by PREVIOUS hop's wait)
      if (wid >= 2) {
        const int kp = (wid - 2) * 256 + ko8;
        if (t == 0) {
          const float* hs = &ctx[m16 * HDIM + kp];
          #pragma unroll
          for (int i = 0; i < 8; ++i) {
            const float* p = hs + 32 * i; bf16x8 a;
            #pragma unroll
            for (int j = 0; j < 8; ++j) a[j] = (__bf16)p[j];
            afrag[i] = a;
          }
        } else {
          const __bf16* hs = (l < 2) ? &hbuf[((prev * 2 + l) * 16 + m16) * HDIM + kp]
                                     : &h2[((size_t)(t - 1) * 16 + m16) * HDIM + kp];
          #pragma unroll
          for (int i = 0; i < 8; ++i) afrag[i] = frag_ld(hs + 32 * i);
        }
      }
      if (wid == 0 && hop > 0) waitFlags<1>(flags, hop, lane);  // all WGs finished hop-1
      __syncthreads();
      // waves 0,1: load x fragments (only ready after the flag wait)
      if (wid < 2) {
        const int kp = wid * 256 + ko8;
        if (l == 0) {
          if (t == 0) {
            const int s = sid[m16];
            const float* xs = &stab[s * HDIM + kp];
            #pragma unroll
            for (int i = 0; i < 8; ++i) {
              const float* p = xs + 32 * i; bf16x8 a;
              #pragma unroll
              for (int j = 0; j < 8; ++j) a[j] = (__bf16)p[j];
              afrag[i] = a;
            }
          } else {
            const __bf16* xs = &h2[((size_t)(t - 1) * 16 + m16) * HDIM + kp];
            #pragma unroll
            for (int i = 0; i < 8; ++i) afrag[i] = frag_ld(xs + 32 * i);
          }
        } else {
          const __bf16* xs = &hbuf[((cur * 2 + (l - 1)) * 16 + m16) * HDIM + kp];
          #pragma unroll
          for (int i = 0; i < 8; ++i) afrag[i] = frag_ld(xs + 32 * i);
        }
      }
      // MFMA over this wave's K-quarter: C[m=batch][n=gate row]
      f32x4 acc = {0.f, 0.f, 0.f, 0.f};
      const __bf16* wrow = &Wlds[(l * 16 + m16) * WROW + wid * 256 + ko8];
      #pragma unroll
      for (int i = 0; i < 8; ++i) {
        bf16x8 b = *(const bf16x8*)(wrow + 32 * i);
        acc = __builtin_amdgcn_mfma_f32_16x16x32_bf16(afrag[i], b, acc, 0, 0, 0);
      }
      #pragma unroll
      for (int rr2 = 0; rr2 < 4; ++rr2)
        pC[(wid * 16 + ((lane >> 4) * 4 + rr2)) * 17 + m16] = acc[rr2];
      __syncthreads();

      // wave 0: cross-wave reduce + LSTM pointwise + publish h slice + release flag
      if (wid == 0) {
        const int m = lane >> 2, u = lane & 3;
        float g[4];
        #pragma unroll
        for (int q = 0; q < 4; ++q) {
          float s = 0.f;
          #pragma unroll
          for (int w = 0; w < 4; ++w) s += pC[(w * 16 + m) * 17 + q * 4 + u];
          g[q] = s + biasL[l * 16 + q * 4 + u];
        }
        const int cidx = (l * 16 + m) * 4 + u;
        float c  = cst[cidx];
        float ig = sigm_f(g[0]), fg = sigm_f(g[1]), gg = tanh_f(g[2]), og = sigm_f(g[3]);
        float cn = fg * c + ig * gg;
        float hn = og * tanh_f(cn);
        cst[cidx] = cn;
        // pack the 4 units of row m into 8B (units ascend with byte address)
        union { __bf16 b; unsigned short s; } cv; cv.b = (__bf16)hn;
        unsigned int p2 = (unsigned int)cv.s |
                          ((unsigned int)(unsigned short)__shfl_xor((int)cv.s, 1) << 16);
        unsigned long long p4 = (unsigned long long)p2 |
                          ((unsigned long long)(unsigned int)__shfl_xor((int)p2, 2) << 32);
        if (u == 0) {
          unsigned long long* dst = (l < 2)
            ? (unsigned long long*)&hbuf[((cur * 2 + l) * 16 + m) * HDIM + 4 * r]
            : (unsigned long long*)&h2[((size_t)t * 16 + m) * HDIM + 4 * r];
          __hip_atomic_store(dst, p4, __ATOMIC_RELAXED, __HIP_MEMORY_SCOPE_AGENT);  // write-through
        }
        asm volatile("s_waitcnt vmcnt(0)" ::: "memory");  // h at coherence point before flag
        if (lane == 0)
          __hip_atomic_store(&flags[r], hop + 1, __ATOMIC_RELAXED, __HIP_MEMORY_SCOPE_AGENT);
      }
      if (++l == NLAYER) { l = 0; ++t; }
    }
  } else if (blk < NREC + NGEMM) {
    // ================= logits GEMM WG: fixed 256-col W_out slice, chunked over steps =================
    __bf16* At = (__bf16*)smem;                   // [CHUNK][16][AROW]
    const int g = blk - NREC;
    const int vbase = g * NCOLS;
    const int n16 = lane & 15;
    const int ko8 = (lane >> 4) * 8;

    // one-time: convert this WG's W_out slice fp32 -> bf16 into workspace (stays L2-hot)
    __bf16* wsl = wbf ? (wbf + (size_t)g * NCOLS * HDIM) : nullptr;
    if (wsl) {
      const float* wsrc = wout + (size_t)vbase * HDIM;
      for (int idx = tid; idx < NCOLS * HDIM / 4; idx += 256) {
        float4 v = *(const float4*)(wsrc + idx * 4);
        union { unsigned long long u; __bf16 b[4]; } r;
        r.b[0] = (__bf16)v.x; r.b[1] = (__bf16)v.y; r.b[2] = (__bf16)v.z; r.b[3] = (__bf16)v.w;
        *(unsigned long long*)(wsl + idx * 4) = r.u;
      }
      __syncthreads();
    }

    for (int ci = 0; ci < NCHUNK; ++ci) {
      const int c0 = ci * CHUNK;
      const int ns = (TSTEPS - c0 < CHUNK) ? (TSTEPS - c0) : CHUNK;
      const int tlast = c0 + ns - 1;
      if (wid == 0) waitFlags<8>(flags, 3 * tlast + 3, lane);   // all steps of this chunk done
      __syncthreads();
      // stage h_top for the chunk into LDS via L2-bypass loads (producers wrote through)
      for (int s = 0; s < ns; ++s) {
        const unsigned long long* src = (const unsigned long long*)&h2[(size_t)(c0 + s) * 16 * HDIM];
        #pragma unroll
        for (int it = 0; it < 8; ++it) {
          int idx = tid + 256 * it;                  // 0..2047 8B units; row = 128 units
          int m = idx >> 7, k4 = idx & 127;
          unsigned long long v = __hip_atomic_load(src + idx, __ATOMIC_RELAXED, __HIP_MEMORY_SCOPE_AGENT);
          *(unsigned long long*)&At[(s * 16 + m) * AROW + k4 * 4] = v;
        }
      }
      __syncthreads();
      for (int nt = wid; nt < 16; nt += 4) {
        const int vrow = vbase + nt * 16 + n16;      // B row = W_out row (B^T trick)
        bf16x8 bfr[16];
        if (wsl) {
          #pragma unroll
          for (int j = 0; j < 16; ++j)
            bfr[j] = *(const bf16x8*)&wsl[(size_t)(nt * 16 + n16) * HDIM + j * 32 + ko8];
        } else {
          #pragma unroll
          for (int j = 0; j < 16; ++j) {
            const float* p = &wout[(size_t)vrow * HDIM + j * 32 + ko8];
            bf16x8 b;
            #pragma unroll
            for (int e = 0; e < 8; ++e) b[e] = (__bf16)p[e];
            bfr[j] = b;
          }
        }
        const float bo = boutg[vrow];
        for (int s = 0; s < ns; ++s) {
          f32x4 acc = {0.f, 0.f, 0.f, 0.f};
          const __bf16* arow = &At[(s * 16 + n16) * AROW + ko8];
          #pragma unroll
          for (int j = 0; j < 16; ++j) {
            bf16x8 a = *(const bf16x8*)(arow + 32 * j);
            acc = __builtin_amdgcn_mfma_f32_16x16x32_bf16(a, bfr[j], acc, 0, 0, 0);
          }
          const int tt = c0 + s;
          #pragma unroll
          for (int rr2 = 0; rr2 < 4; ++rr2) {
            const int m = (lane >> 4) * 4 + rr2;     // C row = batch
            out[((size_t)m * TSTEPS + tt) * VDIM + vrow] = acc[rr2] + bo;
          }
        }
      }
    }
  }
}

extern "C" void kernel_launch(void* const* d_in, const int* in_sizes, int n_in,
                              void* d_out, int out_size, void* d_ws, size_t ws_size,
                              hipStream_t stream) {
  const float* ctx  = (const float*)d_in[0];
  const int*   sid  = (const int*)  d_in[1];
  const float* stab = (const float*)d_in[2];
  const float* wih  = (const float*)d_in[3];
  const float* whh  = (const float*)d_in[4];
  const float* bih  = (const float*)d_in[5];
  const float* bhh  = (const float*)d_in[6];
  const float* wout = (const float*)d_in[7];
  const float* bout = (const float*)d_in[8];
  float* out = (float*)d_out;

  char* ws = (char*)d_ws;
  int*    flags = (int*)ws;                                         // 128 ints (poison = not ready)
  __bf16* h2    = (__bf16*)(ws + 1024);                             // [100][16][512] top-layer history
  size_t  off   = 1024 + (size_t)TSTEPS * 16 * HDIM * 2;
  __bf16* hbuf  = (__bf16*)(ws + off);                              // [2][2][16][512] parity h
  off += 2 * 2 * 16 * HDIM * 2;
  size_t wb_need = off + (size_t)VDIM * HDIM * 2;
  __bf16* wbf = (ws_size >= wb_need) ? (__bf16*)(ws + off) : nullptr;  // [32000][512] bf16 W_out

  (void)in_sizes; (void)n_in; (void)out_size;
  hipFuncSetAttribute((const void*)rgn_kernel, hipFuncAttributeMaxDynamicSharedMemorySize, SMEM_BYTES);
  rgn_kernel<<<dim3(NREC + NGEMM), dim3(256), SMEM_BYTES, stream>>>(
      ctx, sid, stab, wih, whh, bih, bhh, wout, bout, out, flags, h2, hbuf, wbf);
}